// Round 4
// baseline (1707.528 us; speedup 1.0000x reference)
//
#include <hip/hip_runtime.h>
#include <hip/hip_bf16.h>

// Problem constants
#define N_NODES 20000
#define KK 20
#define DD 128
#define HH 4
#define DKK 32
#define EE 128
#define HIDD 512
#define RTOT (N_NODES * KK)   // 400000 rows

using bf16 = __hip_bfloat16;

typedef short s16x8 __attribute__((ext_vector_type(8)));   // 8 bf16 in 4 VGPRs
typedef float f32x4 __attribute__((ext_vector_type(4)));

__device__ __forceinline__ float geluf(float x) {
    return 0.5f * x * (1.0f + erff(x * 0.70710678118654752f));
}

__device__ __forceinline__ float wave_sum(float v) {
#pragma unroll
    for (int o = 32; o > 0; o >>= 1) v += __shfl_down(v, o);
    return __shfl(v, 0);
}

// ---------------------------------------------------------------------------
// Kernel 0: convert FFN weights to transposed bf16 [N][K] layout.
// w1t[n][k] = w1[k][n]  (512 x 128);  w2t[n][k] = w2[k][n]  (128 x 512)
// ---------------------------------------------------------------------------
__global__ __launch_bounds__(256)
void k0_conv(const float* __restrict__ w1, const float* __restrict__ w2,
             bf16* __restrict__ w1t, bf16* __restrict__ w2t)
{
    const int id = blockIdx.x * 256 + threadIdx.x;   // 0 .. 131071
    if (id < HIDD * DD) {
        const int n = id / DD, k = id % DD;          // w1t[n][k]
        w1t[id] = __float2bfloat16(w1[k * HIDD + n]);
    } else {
        const int j = id - HIDD * DD;                // w2t: n<128, k<512
        const int n = j / HIDD, k = j % HIDD;
        w2t[j] = __float2bfloat16(w2[k * DD + n]);
    }
}

// ---------------------------------------------------------------------------
// Kernel 0b: attention + edge weights -> bf16.
// aw = [wqT | wkT | wvT | wqsT | afwT | ewT | fwb(2 blocks)]
// m<6: 128x128 transposed T[n][k]=W[k][n]; m=6,7: fw straight bf16 copy.
// ---------------------------------------------------------------------------
__global__ __launch_bounds__(256)
void k0b_conv(const float* __restrict__ wq, const float* __restrict__ wk,
              const float* __restrict__ wv, const float* __restrict__ wqs,
              const float* __restrict__ afw, const float* __restrict__ ew,
              const float* __restrict__ fw, bf16* __restrict__ aw)
{
    const int id = blockIdx.x * 256 + threadIdx.x;   // 0 .. 131071
    const int m = id >> 14;                          // segment 0..7
    const int r = id & 16383;
    if (m < 6) {
        const int n = r >> 7, k = r & 127;
        const float* src = (m == 0) ? wq : (m == 1) ? wk : (m == 2) ? wv
                         : (m == 3) ? wqs : (m == 4) ? afw : ew;
        aw[id] = __float2bfloat16(src[k * DD + n]);
    } else {
        aw[id] = __float2bfloat16(fw[(m - 6) * 16384 + r]);   // fwb[c*128+d]
    }
}

// ---------------------------------------------------------------------------
// Fused per-node kernel: message + attention + FFN + fuse. One block per node.
// z never touches HBM. All MFMA pad rows (20..31) are garbage-by-design and
// row-confined: MFMA never mixes M-rows; contraction-dim garbage only meets
// zero P columns (softmax masks j>=20) or explicitly zeroed V rows.
//
// LDS overlays (byte offsets, 31776 total -> 5 blocks/CU):
//   efb  [20][136] bf16 @0       stage        -> qb [20][136] (QKV..scores)
//   nhf  [20][132] f32  @5440    stage        -> kb [20][136] @5440
//   Pm   [4][32][40] bf16 @0     (P tiles, overlays qb+kb after scores)
//   obf  [32][136] bf16 @0       (O tile, overlays Pm after PV)
//   us   [20][132] f32  @0       (attn epilogue; later FFN epilogue + x)
//   h1   [32][264] bf16 @0       (FFN hidden chunk; writes rows<20 only)
//   fused[256] f32 @10880, part[2][128] @11904, red[4] @12928   (k4 phase)
//   ts   [20] f32  @16000
//   zs   [20][136] bf16 @16096   (z tile; dead after attn_fc residual)
//   vT   [128][40] bf16 @21536   (V^T; dead after PV) -> xb [20][136] @21536
// ---------------------------------------------------------------------------
#define O_NHF   5440
#define O_KB    5440
#define O_FUSED 10880
#define O_PART  11904
#define O_RED   12928
#define O_TS    16000
#define O_ZS    16096
#define O_VT    21536
#define O_XB    21536
#define SMEM_SZ 31776

__global__ __launch_bounds__(256, 5)
void k_node(const float* __restrict__ nhs, const float* __restrict__ t,
            const float* __restrict__ t_now, const float* __restrict__ ef,
            const float* __restrict__ freq, const float* __restrict__ phase,
            const float* __restrict__ eb,
            const bf16* __restrict__ aw, const float* __restrict__ afb,
            const float* __restrict__ alng, const float* __restrict__ alnb,
            const bf16* __restrict__ w1t, const float* __restrict__ b1,
            const bf16* __restrict__ w2t, const float* __restrict__ b2,
            const float* __restrict__ flng, const float* __restrict__ flnb,
            const float* __restrict__ fb,
            const float* __restrict__ olng, const float* __restrict__ olnb,
            float* __restrict__ out)
{
    __shared__ __align__(16) char smem[SMEM_SZ];
    bf16  (*efb)[136]   = (bf16  (*)[136])(smem);
    bf16  (*qb)[136]    = (bf16  (*)[136])(smem);
    bf16  (*Pm)[32][40] = (bf16  (*)[32][40])(smem);
    bf16  (*obf)[136]   = (bf16  (*)[136])(smem);
    float (*us)[132]    = (float (*)[132])(smem);
    bf16  (*h1)[264]    = (bf16  (*)[264])(smem);
    float (*nhf)[132]   = (float (*)[132])(smem + O_NHF);
    bf16  (*kb)[136]    = (bf16  (*)[136])(smem + O_KB);
    float *fused        = (float*)(smem + O_FUSED);
    float (*part)[128]  = (float (*)[128])(smem + O_PART);
    float *red          = (float*)(smem + O_RED);
    float *ts           = (float*)(smem + O_TS);
    bf16  (*zs)[136]    = (bf16  (*)[136])(smem + O_ZS);
    bf16  (*vT)[40]     = (bf16  (*)[40]) (smem + O_VT);
    bf16  (*xb)[136]    = (bf16  (*)[136])(smem + O_XB);

    const int tid  = threadIdx.x;
    const int wv4  = tid >> 6;          // wave 0..3
    const int lane = tid & 63;
    const int col  = lane & 15;
    const int quad = lane >> 4;         // 0..3
    const int node = blockIdx.x;
    const size_t base = (size_t)node * KK * DD;
    const bf16* ewt = aw + 5 * (DD * DD);
    const bf16* fwb = aw + 6 * (DD * DD);
    const f32x4 fzero = (f32x4){0.f, 0.f, 0.f, 0.f};

    // ===== stage ef (f32->bf16) + nhs (f32) + t =====
    {
        const float4* esrc = (const float4*)(ef + base);    // 640 float4
        const float4* nsrc = (const float4*)(nhs + base);
        for (int i = tid; i < 640; i += 256) {
            const int r = i >> 5, c = (i & 31) * 4;
            const float4 v = esrc[i];
            bf16 tmp[4] = { __float2bfloat16(v.x), __float2bfloat16(v.y),
                            __float2bfloat16(v.z), __float2bfloat16(v.w) };
            *(uint2*)&efb[r][c] = *(const uint2*)tmp;
            *(float4*)&nhf[r][c] = nsrc[i];
        }
        if (tid < KK) ts[tid] = t[node * KK + tid];
    }
    __syncthreads();   // B1

    // ===== edge_fc MFMA + z epilogue (zs separate region; no internal barrier)
    {
        f32x4 eacc[2][2];
#pragma unroll
        for (int mt = 0; mt < 2; mt++)
#pragma unroll
            for (int nt = 0; nt < 2; nt++) eacc[mt][nt] = fzero;
#pragma unroll
        for (int kk = 0; kk < 4; kk++) {
            const int k0 = kk * 32 + quad * 8;
            const s16x8 a0 = *(const s16x8*)&efb[col][k0];
            const s16x8 a1 = *(const s16x8*)&efb[16 + col][k0];  // rows>=20 alias nhf (masked)
#pragma unroll
            for (int nt = 0; nt < 2; nt++) {
                const int n = wv4 * 32 + nt * 16 + col;
                const s16x8 b = *(const s16x8*)&ewt[n * DD + k0];
                eacc[0][nt] = __builtin_amdgcn_mfma_f32_16x16x32_bf16(a0, b, eacc[0][nt], 0, 0, 0);
                eacc[1][nt] = __builtin_amdgcn_mfma_f32_16x16x32_bf16(a1, b, eacc[1][nt], 0, 0, 0);
            }
        }
        const float tn = t_now[0];
#pragma unroll
        for (int nt = 0; nt < 2; nt++) {
            const int n = wv4 * 32 + nt * 16 + col;
            const float bias = eb[n], fq = freq[n], ph = phase[n];
#pragma unroll
            for (int mt = 0; mt < 2; mt++)
#pragma unroll
                for (int r = 0; r < 4; r++) {
                    const int row = mt * 16 + quad * 4 + r;
                    if (row < KK) {
                        const float zz = nhf[row][n] + geluf(eacc[mt][nt][r] + bias)
                                       + __cosf((tn - ts[row]) * fq + ph);
                        zs[row][n] = __float2bfloat16(zz);
                    }
                }
        }
    }
    __syncthreads();   // B2

    // ===== QKV (+self_q): wave wv4 computes z @ W[wv4] =====
    {
        const bf16* Wm = aw + wv4 * (DD * DD);
        f32x4 acc[2][8];
#pragma unroll
        for (int mt = 0; mt < 2; mt++)
#pragma unroll
            for (int nt = 0; nt < 8; nt++) acc[mt][nt] = fzero;
#pragma unroll
        for (int kk = 0; kk < 4; kk++) {
            const int k0 = kk * 32 + quad * 8;
            const s16x8 a0 = *(const s16x8*)&zs[col][k0];
            const s16x8 a1 = *(const s16x8*)&zs[16 + col][k0];   // rows>=20 alias (masked)
#pragma unroll
            for (int nt = 0; nt < 8; nt++) {
                const s16x8 b = *(const s16x8*)&Wm[(nt * 16 + col) * DD + k0];
                acc[0][nt] = __builtin_amdgcn_mfma_f32_16x16x32_bf16(a0, b, acc[0][nt], 0, 0, 0);
                acc[1][nt] = __builtin_amdgcn_mfma_f32_16x16x32_bf16(a1, b, acc[1][nt], 0, 0, 0);
            }
        }
        if (wv4 < 2) {
            bf16 (*dst)[136] = (wv4 == 0) ? qb : kb;             // rows 0..18
#pragma unroll
            for (int mt = 0; mt < 2; mt++)
#pragma unroll
                for (int nt = 0; nt < 8; nt++)
#pragma unroll
                    for (int r = 0; r < 4; r++) {
                        const int row = mt * 16 + quad * 4 + r;
                        if (row >= 19) continue;
                        dst[row][nt * 16 + col] = __float2bfloat16(acc[mt][nt][r]);
                    }
        } else if (wv4 == 2) {                                   // V -> vT[n][j]; j>=20 zeroed
#pragma unroll
            for (int mt = 0; mt < 2; mt++)
#pragma unroll
                for (int nt = 0; nt < 8; nt++)
#pragma unroll
                    for (int r = 0; r < 4; r++) {
                        const int row = mt * 16 + quad * 4 + r;
                        if (row == 19) continue;
                        vT[nt * 16 + col][row] =
                            (row < 19) ? __float2bfloat16(acc[mt][nt][r]) : __float2bfloat16(0.f);
                    }
        } else if (quad == 0) {                                  // wave 3: self_q = z[19] @ wqs
#pragma unroll
            for (int nt = 0; nt < 8; nt++) {
                const int n = nt * 16 + col;
                const bf16 s = __float2bfloat16(acc[1][nt][3]);  // D row 19
                qb[19][n] = s; kb[19][n] = s; vT[n][19] = s;
            }
        }
    }
    __syncthreads();   // B3

    // ===== scores via MFMA + in-register softmax (head h = wv4) =====
    float p0[2][4], p1[2][4];
    {
        const int hb = wv4 * DKK;
        const int k0 = quad * 8;
        const s16x8 qa0 = *(const s16x8*)&qb[col][hb + k0];
        const s16x8 qa1 = *(const s16x8*)&qb[16 + col][hb + k0];
        const s16x8 kf0 = *(const s16x8*)&kb[col][hb + k0];
        const s16x8 kf1 = *(const s16x8*)&kb[16 + col][hb + k0];
        f32x4 sacc[2][2];
        sacc[0][0] = __builtin_amdgcn_mfma_f32_16x16x32_bf16(qa0, kf0, fzero, 0, 0, 0);
        sacc[0][1] = __builtin_amdgcn_mfma_f32_16x16x32_bf16(qa0, kf1, fzero, 0, 0, 0);
        sacc[1][0] = __builtin_amdgcn_mfma_f32_16x16x32_bf16(qa1, kf0, fzero, 0, 0, 0);
        sacc[1][1] = __builtin_amdgcn_mfma_f32_16x16x32_bf16(qa1, kf1, fzero, 0, 0, 0);

        const float scale = 0.17677669529663687f;
#pragma unroll
        for (int mt = 0; mt < 2; mt++)
#pragma unroll
            for (int r = 0; r < 4; r++) {
                const float s0 = sacc[mt][0][r] * scale;
                const float s1 = sacc[mt][1][r] * scale;
                float mx = fmaxf(s0, (col < 4) ? s1 : -1e30f);
#pragma unroll
                for (int o = 1; o < 16; o <<= 1) mx = fmaxf(mx, __shfl_xor(mx, o));
                const float e0 = __expf(s0 - mx);
                const float e1 = (col < 4) ? __expf(s1 - mx) : 0.f;
                float sm = e0 + e1;
#pragma unroll
                for (int o = 1; o < 16; o <<= 1) sm += __shfl_xor(sm, o);
                const float inv = 1.0f / sm;
                p0[mt][r] = e0 * inv;
                p1[mt][r] = e1 * inv;
            }
    }
    __syncthreads();   // B4 (qb/kb reads done -> Pm may overwrite)

    // ===== write P (bf16), PV via MFMA =====
#pragma unroll
    for (int mt = 0; mt < 2; mt++)
#pragma unroll
        for (int r = 0; r < 4; r++) {
            const int i = mt * 16 + quad * 4 + r;
            Pm[wv4][i][col]      = __float2bfloat16(p0[mt][r]);
            Pm[wv4][i][16 + col] = __float2bfloat16(p1[mt][r]);
        }
    // intra-wave write->read on Pm[wv4]: compiler orders via lgkmcnt
    f32x4 oacc[2][2];
    {
        const int hb = wv4 * DKK;
        const int k0 = quad * 8;
        const s16x8 pa0 = *(const s16x8*)&Pm[wv4][col][k0];
        const s16x8 pa1 = *(const s16x8*)&Pm[wv4][16 + col][k0];
        const s16x8 vb0 = *(const s16x8*)&vT[hb + col][k0];
        const s16x8 vb1 = *(const s16x8*)&vT[hb + 16 + col][k0];
        oacc[0][0] = __builtin_amdgcn_mfma_f32_16x16x32_bf16(pa0, vb0, fzero, 0, 0, 0);
        oacc[0][1] = __builtin_amdgcn_mfma_f32_16x16x32_bf16(pa0, vb1, fzero, 0, 0, 0);
        oacc[1][0] = __builtin_amdgcn_mfma_f32_16x16x32_bf16(pa1, vb0, fzero, 0, 0, 0);
        oacc[1][1] = __builtin_amdgcn_mfma_f32_16x16x32_bf16(pa1, vb1, fzero, 0, 0, 0);
    }
    __syncthreads();   // B5 (Pm/vT reads done -> obf may overwrite)

    {
        const int hb = wv4 * DKK;
#pragma unroll
        for (int mt = 0; mt < 2; mt++)
#pragma unroll
            for (int nt = 0; nt < 2; nt++)
#pragma unroll
                for (int r = 0; r < 4; r++)
                    obf[mt * 16 + quad * 4 + r][hb + nt * 16 + col] =
                        __float2bfloat16(oacc[mt][nt][r]);
    }
    __syncthreads();   // B6

    // ===== attn_fc: X = O @ afwT + afb + z; then LN -> xb =====
    {
        const bf16* AF = aw + 4 * (DD * DD);
        f32x4 facc[2][2];
#pragma unroll
        for (int mt = 0; mt < 2; mt++)
#pragma unroll
            for (int nt = 0; nt < 2; nt++) facc[mt][nt] = fzero;
#pragma unroll
        for (int kk = 0; kk < 4; kk++) {
            const int k0 = kk * 32 + quad * 8;
            const s16x8 a0 = *(const s16x8*)&obf[col][k0];
            const s16x8 a1 = *(const s16x8*)&obf[16 + col][k0];
#pragma unroll
            for (int nt = 0; nt < 2; nt++) {
                const int n = (wv4 * 2 + nt) * 16 + col;
                const s16x8 b = *(const s16x8*)&AF[n * DD + k0];
                facc[0][nt] = __builtin_amdgcn_mfma_f32_16x16x32_bf16(a0, b, facc[0][nt], 0, 0, 0);
                facc[1][nt] = __builtin_amdgcn_mfma_f32_16x16x32_bf16(a1, b, facc[1][nt], 0, 0, 0);
            }
        }
        __syncthreads();   // B7 (obf reads done -> us may overwrite)

#pragma unroll
        for (int mt = 0; mt < 2; mt++)
#pragma unroll
            for (int nt = 0; nt < 2; nt++) {
                const int n = (wv4 * 2 + nt) * 16 + col;
                const float bias = afb[n];
#pragma unroll
                for (int r = 0; r < 4; r++) {
                    const int i = mt * 16 + quad * 4 + r;
                    if (i >= KK) continue;
                    us[i][n] = facc[mt][nt][r] + bias + __bfloat162float(zs[i][n]);
                }
            }
    }
    __syncthreads();   // B8

    for (int i = wv4; i < KK; i += 4) {        // attn LN -> xb (vT dead)
        const float a0 = us[i][lane], a1 = us[i][lane + 64];
        const float s  = wave_sum(a0 + a1);
        const float sq = wave_sum(a0 * a0 + a1 * a1);
        const float mean = s * (1.0f / DD);
        const float var  = sq * (1.0f / DD) - mean * mean;
        const float inv  = rsqrtf(var + 1e-5f);
        xb[i][lane]      = __float2bfloat16((a0 - mean) * inv * alng[lane] + alnb[lane]);
        xb[i][lane + 64] = __float2bfloat16((a1 - mean) * inv * alng[lane + 64] + alnb[lane + 64]);
    }
    __syncthreads();   // B9 (us dead -> h1 region free)

    // ===== FFN in two 256-col chunks; acc2 accumulates across chunks =====
    f32x4 acc2[2][2];
#pragma unroll
    for (int mt = 0; mt < 2; mt++)
#pragma unroll
        for (int nt = 0; nt < 2; nt++) acc2[mt][nt] = fzero;

#pragma unroll
    for (int ch = 0; ch < 2; ch++) {
        {   // phase A: h1 = relu(x @ W1 + b1), cols [ch*256, ch*256+256)
            f32x4 acc[2][4];
#pragma unroll
            for (int mt = 0; mt < 2; mt++)
#pragma unroll
                for (int nt = 0; nt < 4; nt++) acc[mt][nt] = fzero;
#pragma unroll
            for (int kk = 0; kk < 4; kk++) {
                const int k0 = kk * 32 + quad * 8;
                const s16x8 a0 = *(const s16x8*)&xb[col][k0];
                const s16x8 a1 = *(const s16x8*)&xb[16 + col][k0];   // rows>=20 alias (masked)
#pragma unroll
                for (int nt = 0; nt < 4; nt++) {
                    const int n = ch * 256 + wv4 * 64 + nt * 16 + col;
                    const s16x8 b = *(const s16x8*)&w1t[n * DD + k0];
                    acc[0][nt] = __builtin_amdgcn_mfma_f32_16x16x32_bf16(a0, b, acc[0][nt], 0, 0, 0);
                    acc[1][nt] = __builtin_amdgcn_mfma_f32_16x16x32_bf16(a1, b, acc[1][nt], 0, 0, 0);
                }
            }
#pragma unroll
            for (int nt = 0; nt < 4; nt++) {
                const int nl = wv4 * 64 + nt * 16 + col;
                const float bias = b1[ch * 256 + nl];
#pragma unroll
                for (int mt = 0; mt < 2; mt++)
#pragma unroll
                    for (int r = 0; r < 4; r++) {
                        const int row = mt * 16 + quad * 4 + r;
                        if (row < KK)
                            h1[row][nl] = __float2bfloat16(fmaxf(acc[mt][nt][r] + bias, 0.f));
                    }
            }
        }
        __syncthreads();   // B10/B12

        {   // phase B: acc2 += h1 @ W2[k-chunk]
#pragma unroll
            for (int kk = 0; kk < 8; kk++) {
                const int k0l = kk * 32 + quad * 8;
                const s16x8 a0 = *(const s16x8*)&h1[col][k0l];
                const s16x8 a1 = *(const s16x8*)&h1[16 + col][k0l];  // rows>=20 garbage (masked)
#pragma unroll
                for (int nt = 0; nt < 2; nt++) {
                    const int n = wv4 * 32 + nt * 16 + col;
                    const s16x8 b = *(const s16x8*)&w2t[n * HIDD + ch * 256 + k0l];
                    acc2[0][nt] = __builtin_amdgcn_mfma_f32_16x16x32_bf16(a0, b, acc2[0][nt], 0, 0, 0);
                    acc2[1][nt] = __builtin_amdgcn_mfma_f32_16x16x32_bf16(a1, b, acc2[1][nt], 0, 0, 0);
                }
            }
        }
        __syncthreads();   // B11/B13 (h1 reads done)
    }

    // FFN epilogue: u = acc2 + b2 + x  (us overlays h1 written region; reads done)
#pragma unroll
    for (int mt = 0; mt < 2; mt++)
#pragma unroll
        for (int nt = 0; nt < 2; nt++) {
            const int n = wv4 * 32 + nt * 16 + col;
            const float bias = b2[n];
#pragma unroll
            for (int r = 0; r < 4; r++) {
                const int i = mt * 16 + quad * 4 + r;
                if (i >= KK) continue;
                us[i][n] = acc2[mt][nt][r] + bias + __bfloat162float(xb[i][n]);
            }
        }
    __syncthreads();   // B14

    for (int i = wv4; i < KK; i += 4) {       // FFN LN, in place (x in f32)
        const float a0 = us[i][lane], a1 = us[i][lane + 64];
        const float s  = wave_sum(a0 + a1);
        const float sq = wave_sum(a0 * a0 + a1 * a1);
        const float mean = s * (1.0f / DD);
        const float var  = sq * (1.0f / DD) - mean * mean;
        const float inv  = rsqrtf(var + 1e-5f);
        us[i][lane]      = (a0 - mean) * inv * flng[lane] + flnb[lane];
        us[i][lane + 64] = (a1 - mean) * inv * flng[lane + 64] + flnb[lane + 64];
    }
    __syncthreads();   // B15

    // ===== fuse: [x_self | mean(neighbors)] @ fw + gelu + residual + LN =====
    if (tid < DD) {
        fused[tid] = us[19][tid];
    } else {
        const int d = tid - DD;
        float nb = 0.f;
#pragma unroll
        for (int i = 0; i < KK - 1; i++) nb += us[i][d];
        fused[DD + d] = nb * (1.0f / (KK - 1));
    }
    __syncthreads();   // B16

    {
        const int d = tid & 127, hb2 = tid >> 7;
        float a = 0.f;
#pragma unroll 8
        for (int ci = 0; ci < 128; ci++) {
            const int c = hb2 * 128 + ci;
            a += fused[c] * __bfloat162float(fwb[c * DD + d]);
        }
        part[hb2][d] = a;
    }
    __syncthreads();   // B17

    float y = 0.f;
    if (tid < DD) {
        y = geluf(part[0][tid] + part[1][tid] + fb[tid]) + nhs[base + (KK - 1) * DD + tid];
        float s = y, sq = y * y;
#pragma unroll
        for (int o = 32; o > 0; o >>= 1) {
            s += __shfl_down(s, o);
            sq += __shfl_down(sq, o);
        }
        const int wid = tid >> 6, ln = tid & 63;
        if (ln == 0) { red[wid] = s; red[2 + wid] = sq; }
    }
    __syncthreads();   // B18
    if (tid < DD) {
        const float tsm = red[0] + red[1], tsq = red[2] + red[3];
        const float mean = tsm * (1.0f / DD);
        const float var  = tsq * (1.0f / DD) - mean * mean;
        const float inv  = rsqrtf(var + 1e-5f);
        out[node * DD + tid] = (y - mean) * inv * olng[tid] + olnb[tid];
    }
}

// ---------------------------------------------------------------------------
extern "C" void kernel_launch(void* const* d_in, const int* in_sizes, int n_in,
                              void* d_out, int out_size, void* d_ws, size_t ws_size,
                              hipStream_t stream)
{
    const float* nhs   = (const float*)d_in[0];
    const float* t     = (const float*)d_in[1];
    const float* tnow  = (const float*)d_in[2];
    const float* ef    = (const float*)d_in[3];
    const float* freq  = (const float*)d_in[4];
    const float* phase = (const float*)d_in[5];
    const float* ew    = (const float*)d_in[6];
    const float* eb    = (const float*)d_in[7];
    const float* wq    = (const float*)d_in[8];
    const float* wk    = (const float*)d_in[9];
    const float* wv    = (const float*)d_in[10];
    const float* wqs   = (const float*)d_in[11];
    const float* afw   = (const float*)d_in[12];
    const float* afb   = (const float*)d_in[13];
    const float* alng  = (const float*)d_in[14];
    const float* alnb  = (const float*)d_in[15];
    const float* w1    = (const float*)d_in[16];
    const float* b1    = (const float*)d_in[17];
    const float* w2    = (const float*)d_in[18];
    const float* b2    = (const float*)d_in[19];
    const float* flng  = (const float*)d_in[20];
    const float* flnb  = (const float*)d_in[21];
    const float* fw    = (const float*)d_in[22];
    const float* fb    = (const float*)d_in[23];
    const float* olng  = (const float*)d_in[24];
    const float* olnb  = (const float*)d_in[25];
    float* out = (float*)d_out;

    bf16* w1t = (bf16*)d_ws;                 // [512][128]  131072 B
    bf16* w2t = w1t + HIDD * DD;             // [128][512]  131072 B
    bf16* aw  = w2t + DD * HIDD;             // 8 x 16384 bf16 (6 transposed + fw)

    k0_conv<<<dim3(2 * HIDD * DD / 256), dim3(256), 0, stream>>>(w1, w2, w1t, w2t);
    k0b_conv<<<dim3(8 * DD * DD / 256), dim3(256), 0, stream>>>(wq, wk, wv, wqs, afw, ew, fw, aw);
    k_node<<<dim3(N_NODES), dim3(256), 0, stream>>>(
        nhs, t, tnow, ef, freq, phase, eb, aw, afb, alng, alnb,
        w1t, b1, w2t, b2, flng, flnb, fb, olng, olnb, out);
}

// Round 5
// 1494.888 us; speedup vs baseline: 1.1422x; 1.1422x over previous
//
#include <hip/hip_runtime.h>
#include <hip/hip_bf16.h>

// Problem constants
#define N_NODES 20000
#define KK 20
#define DD 128
#define HH 4
#define DKK 32
#define EE 128
#define HIDD 512
#define RTOT (N_NODES * KK)   // 400000 rows

using bf16 = __hip_bfloat16;

typedef short s16x8 __attribute__((ext_vector_type(8)));   // 8 bf16 in 4 VGPRs
typedef float f32x4 __attribute__((ext_vector_type(4)));

__device__ __forceinline__ float geluf(float x) {
    return 0.5f * x * (1.0f + erff(x * 0.70710678118654752f));
}

__device__ __forceinline__ float wave_sum(float v) {
#pragma unroll
    for (int o = 32; o > 0; o >>= 1) v += __shfl_down(v, o);
    return __shfl(v, 0);
}

// ---------------------------------------------------------------------------
// Kernel 0: convert FFN weights to transposed bf16 [N][K] layout.
// ---------------------------------------------------------------------------
__global__ __launch_bounds__(256)
void k0_conv(const float* __restrict__ w1, const float* __restrict__ w2,
             bf16* __restrict__ w1t, bf16* __restrict__ w2t)
{
    const int id = blockIdx.x * 256 + threadIdx.x;   // 0 .. 131071
    if (id < HIDD * DD) {
        const int n = id / DD, k = id % DD;          // w1t[n][k]
        w1t[id] = __float2bfloat16(w1[k * HIDD + n]);
    } else {
        const int j = id - HIDD * DD;                // w2t: n<128, k<512
        const int n = j / HIDD, k = j % HIDD;
        w2t[j] = __float2bfloat16(w2[k * DD + n]);
    }
}

// ---------------------------------------------------------------------------
// Kernel 0b: attention + edge weights -> bf16.
// aw = [wqT | wkT | wvT | wqsT | afwT | ewT | fwb(2 blocks)]
// ---------------------------------------------------------------------------
__global__ __launch_bounds__(256)
void k0b_conv(const float* __restrict__ wq, const float* __restrict__ wk,
              const float* __restrict__ wv, const float* __restrict__ wqs,
              const float* __restrict__ afw, const float* __restrict__ ew,
              const float* __restrict__ fw, bf16* __restrict__ aw)
{
    const int id = blockIdx.x * 256 + threadIdx.x;   // 0 .. 131071
    const int m = id >> 14;                          // segment 0..7
    const int r = id & 16383;
    if (m < 6) {
        const int n = r >> 7, k = r & 127;
        const float* src = (m == 0) ? wq : (m == 1) ? wk : (m == 2) ? wv
                         : (m == 3) ? wqs : (m == 4) ? afw : ew;
        aw[id] = __float2bfloat16(src[k * DD + n]);
    } else {
        aw[id] = __float2bfloat16(fw[(m - 6) * 16384 + r]);   // fwb[c*128+d]
    }
}

// ---------------------------------------------------------------------------
// Fused per-node kernel. One block per node; z never touches HBM.
// Register budget: __launch_bounds__(256,4) -> 128 VGPR cap, no spill
// (R4's (256,5) = ~96-VGPR cap spilled 1.3 GB of scratch -> whole-kernel
// scratch-bound). QKV phase additionally split into two half-passes
// (acc[2][4] live instead of acc[2][8]).
//
// LDS overlays (byte offsets, 31776 total):
//   efb  [20][136] bf16 @0       stage        -> qb [20][136] (QKV..scores)
//   nhf  [20][132] f32  @5440    stage        -> kb [20][136] @5440
//   Pm   [4][32][40] bf16 @0     (overlays qb+kb after scores)
//   obf  [32][136] bf16 @0       (overlays Pm after PV)
//   us   [20][132] f32  @0       (attn epilogue; later FFN epilogue)
//   h1   [32][264] bf16 @0       (FFN hidden chunk; rows<20 written)
//   fused[256] f32 @10880, part[2][128] @11904, red[4] @12928   (fuse phase)
//   ts   [20] f32  @16000
//   zs   [20][136] bf16 @16096   (z tile; dead after attn_fc residual)
//   vT   [128][40] bf16 @21536   (V^T; dead after PV) -> xb [20][136] @21536
// ---------------------------------------------------------------------------
#define O_NHF   5440
#define O_KB    5440
#define O_FUSED 10880
#define O_PART  11904
#define O_RED   12928
#define O_TS    16000
#define O_ZS    16096
#define O_VT    21536
#define O_XB    21536
#define SMEM_SZ 31776

__global__ __launch_bounds__(256, 4)
void k_node(const float* __restrict__ nhs, const float* __restrict__ t,
            const float* __restrict__ t_now, const float* __restrict__ ef,
            const float* __restrict__ freq, const float* __restrict__ phase,
            const float* __restrict__ eb,
            const bf16* __restrict__ aw, const float* __restrict__ afb,
            const float* __restrict__ alng, const float* __restrict__ alnb,
            const bf16* __restrict__ w1t, const float* __restrict__ b1,
            const bf16* __restrict__ w2t, const float* __restrict__ b2,
            const float* __restrict__ flng, const float* __restrict__ flnb,
            const float* __restrict__ fb,
            const float* __restrict__ olng, const float* __restrict__ olnb,
            float* __restrict__ out)
{
    __shared__ __align__(16) char smem[SMEM_SZ];
    bf16  (*efb)[136]   = (bf16  (*)[136])(smem);
    bf16  (*qb)[136]    = (bf16  (*)[136])(smem);
    bf16  (*Pm)[32][40] = (bf16  (*)[32][40])(smem);
    bf16  (*obf)[136]   = (bf16  (*)[136])(smem);
    float (*us)[132]    = (float (*)[132])(smem);
    bf16  (*h1)[264]    = (bf16  (*)[264])(smem);
    float (*nhf)[132]   = (float (*)[132])(smem + O_NHF);
    bf16  (*kb)[136]    = (bf16  (*)[136])(smem + O_KB);
    float *fused        = (float*)(smem + O_FUSED);
    float (*part)[128]  = (float (*)[128])(smem + O_PART);
    float *red          = (float*)(smem + O_RED);
    float *ts           = (float*)(smem + O_TS);
    bf16  (*zs)[136]    = (bf16  (*)[136])(smem + O_ZS);
    bf16  (*vT)[40]     = (bf16  (*)[40]) (smem + O_VT);
    bf16  (*xb)[136]    = (bf16  (*)[136])(smem + O_XB);

    const int tid  = threadIdx.x;
    const int wv4  = tid >> 6;          // wave 0..3
    const int lane = tid & 63;
    const int col  = lane & 15;
    const int quad = lane >> 4;         // 0..3
    const int node = blockIdx.x;
    const size_t base = (size_t)node * KK * DD;
    const bf16* ewt = aw + 5 * (DD * DD);
    const bf16* fwb = aw + 6 * (DD * DD);
    const f32x4 fzero = (f32x4){0.f, 0.f, 0.f, 0.f};

    // ===== stage ef (f32->bf16) + nhs (f32) + t =====
    {
        const float4* esrc = (const float4*)(ef + base);    // 640 float4
        const float4* nsrc = (const float4*)(nhs + base);
        for (int i = tid; i < 640; i += 256) {
            const int r = i >> 5, c = (i & 31) * 4;
            const float4 v = esrc[i];
            bf16 tmp[4] = { __float2bfloat16(v.x), __float2bfloat16(v.y),
                            __float2bfloat16(v.z), __float2bfloat16(v.w) };
            *(uint2*)&efb[r][c] = *(const uint2*)tmp;
            *(float4*)&nhf[r][c] = nsrc[i];
        }
        if (tid < KK) ts[tid] = t[node * KK + tid];
    }
    __syncthreads();   // B1

    // ===== edge_fc MFMA + z epilogue =====
    {
        f32x4 eacc[2][2];
#pragma unroll
        for (int mt = 0; mt < 2; mt++)
#pragma unroll
            for (int nt = 0; nt < 2; nt++) eacc[mt][nt] = fzero;
#pragma unroll
        for (int kk = 0; kk < 4; kk++) {
            const int k0 = kk * 32 + quad * 8;
            const s16x8 a0 = *(const s16x8*)&efb[col][k0];
            const s16x8 a1 = *(const s16x8*)&efb[16 + col][k0];  // rows>=20 alias nhf (masked)
#pragma unroll
            for (int nt = 0; nt < 2; nt++) {
                const int n = wv4 * 32 + nt * 16 + col;
                const s16x8 b = *(const s16x8*)&ewt[n * DD + k0];
                eacc[0][nt] = __builtin_amdgcn_mfma_f32_16x16x32_bf16(a0, b, eacc[0][nt], 0, 0, 0);
                eacc[1][nt] = __builtin_amdgcn_mfma_f32_16x16x32_bf16(a1, b, eacc[1][nt], 0, 0, 0);
            }
        }
        const float tn = t_now[0];
#pragma unroll
        for (int nt = 0; nt < 2; nt++) {
            const int n = wv4 * 32 + nt * 16 + col;
            const float bias = eb[n], fq = freq[n], ph = phase[n];
#pragma unroll
            for (int mt = 0; mt < 2; mt++)
#pragma unroll
                for (int r = 0; r < 4; r++) {
                    const int row = mt * 16 + quad * 4 + r;
                    if (row < KK) {
                        const float zz = nhf[row][n] + geluf(eacc[mt][nt][r] + bias)
                                       + __cosf((tn - ts[row]) * fq + ph);
                        zs[row][n] = __float2bfloat16(zz);
                    }
                }
        }
    }
    __syncthreads();   // B2

    // ===== QKV (+self_q): wave wv4 computes z @ W[wv4], two half-passes =====
    {
        const bf16* Wm = aw + wv4 * (DD * DD);
#pragma unroll
        for (int half = 0; half < 2; half++) {
            f32x4 acc[2][4];
#pragma unroll
            for (int mt = 0; mt < 2; mt++)
#pragma unroll
                for (int nt = 0; nt < 4; nt++) acc[mt][nt] = fzero;
#pragma unroll
            for (int kk = 0; kk < 4; kk++) {
                const int k0 = kk * 32 + quad * 8;
                const s16x8 a0 = *(const s16x8*)&zs[col][k0];
                const s16x8 a1 = *(const s16x8*)&zs[16 + col][k0];   // rows>=20 alias (masked)
#pragma unroll
                for (int nt = 0; nt < 4; nt++) {
                    const int n = (half * 4 + nt) * 16 + col;
                    const s16x8 b = *(const s16x8*)&Wm[n * DD + k0];
                    acc[0][nt] = __builtin_amdgcn_mfma_f32_16x16x32_bf16(a0, b, acc[0][nt], 0, 0, 0);
                    acc[1][nt] = __builtin_amdgcn_mfma_f32_16x16x32_bf16(a1, b, acc[1][nt], 0, 0, 0);
                }
            }
            if (wv4 < 2) {
                bf16 (*dst)[136] = (wv4 == 0) ? qb : kb;             // rows 0..18
#pragma unroll
                for (int mt = 0; mt < 2; mt++)
#pragma unroll
                    for (int nt = 0; nt < 4; nt++)
#pragma unroll
                        for (int r = 0; r < 4; r++) {
                            const int row = mt * 16 + quad * 4 + r;
                            if (row >= 19) continue;
                            dst[row][(half * 4 + nt) * 16 + col] = __float2bfloat16(acc[mt][nt][r]);
                        }
            } else if (wv4 == 2) {                                   // V -> vT[n][j]; j>=20 zeroed
#pragma unroll
                for (int mt = 0; mt < 2; mt++)
#pragma unroll
                    for (int nt = 0; nt < 4; nt++)
#pragma unroll
                        for (int r = 0; r < 4; r++) {
                            const int row = mt * 16 + quad * 4 + r;
                            if (row == 19) continue;
                            vT[(half * 4 + nt) * 16 + col][row] =
                                (row < 19) ? __float2bfloat16(acc[mt][nt][r]) : __float2bfloat16(0.f);
                        }
            } else if (quad == 0) {                                  // wave 3: self_q = z[19] @ wqs
#pragma unroll
                for (int nt = 0; nt < 4; nt++) {
                    const int n = (half * 4 + nt) * 16 + col;
                    const bf16 s = __float2bfloat16(acc[1][nt][3]);  // D row 19 (mt=1,quad=0,r=3)
                    qb[19][n] = s; kb[19][n] = s; vT[n][19] = s;
                }
            }
        }
    }
    __syncthreads();   // B3

    // ===== scores via MFMA + in-register softmax (head h = wv4) =====
    float p0[2][4], p1[2][4];
    {
        const int hb = wv4 * DKK;
        const int k0 = quad * 8;
        const s16x8 qa0 = *(const s16x8*)&qb[col][hb + k0];
        const s16x8 qa1 = *(const s16x8*)&qb[16 + col][hb + k0];
        const s16x8 kf0 = *(const s16x8*)&kb[col][hb + k0];
        const s16x8 kf1 = *(const s16x8*)&kb[16 + col][hb + k0];
        f32x4 sacc[2][2];
        sacc[0][0] = __builtin_amdgcn_mfma_f32_16x16x32_bf16(qa0, kf0, fzero, 0, 0, 0);
        sacc[0][1] = __builtin_amdgcn_mfma_f32_16x16x32_bf16(qa0, kf1, fzero, 0, 0, 0);
        sacc[1][0] = __builtin_amdgcn_mfma_f32_16x16x32_bf16(qa1, kf0, fzero, 0, 0, 0);
        sacc[1][1] = __builtin_amdgcn_mfma_f32_16x16x32_bf16(qa1, kf1, fzero, 0, 0, 0);

        const float scale = 0.17677669529663687f;
#pragma unroll
        for (int mt = 0; mt < 2; mt++)
#pragma unroll
            for (int r = 0; r < 4; r++) {
                const float s0 = sacc[mt][0][r] * scale;
                const float s1 = sacc[mt][1][r] * scale;
                float mx = fmaxf(s0, (col < 4) ? s1 : -1e30f);
#pragma unroll
                for (int o = 1; o < 16; o <<= 1) mx = fmaxf(mx, __shfl_xor(mx, o));
                const float e0 = __expf(s0 - mx);
                const float e1 = (col < 4) ? __expf(s1 - mx) : 0.f;
                float sm = e0 + e1;
#pragma unroll
                for (int o = 1; o < 16; o <<= 1) sm += __shfl_xor(sm, o);
                const float inv = 1.0f / sm;
                p0[mt][r] = e0 * inv;
                p1[mt][r] = e1 * inv;
            }
    }
    __syncthreads();   // B4 (qb/kb reads done -> Pm may overwrite)

    // ===== write P (bf16), PV via MFMA =====
#pragma unroll
    for (int mt = 0; mt < 2; mt++)
#pragma unroll
        for (int r = 0; r < 4; r++) {
            const int i = mt * 16 + quad * 4 + r;
            Pm[wv4][i][col]      = __float2bfloat16(p0[mt][r]);
            Pm[wv4][i][16 + col] = __float2bfloat16(p1[mt][r]);
        }
    // intra-wave write->read on Pm[wv4]: compiler orders via lgkmcnt
    f32x4 oacc[2][2];
    {
        const int hb = wv4 * DKK;
        const int k0 = quad * 8;
        const s16x8 pa0 = *(const s16x8*)&Pm[wv4][col][k0];
        const s16x8 pa1 = *(const s16x8*)&Pm[wv4][16 + col][k0];
        const s16x8 vb0 = *(const s16x8*)&vT[hb + col][k0];
        const s16x8 vb1 = *(const s16x8*)&vT[hb + 16 + col][k0];
        oacc[0][0] = __builtin_amdgcn_mfma_f32_16x16x32_bf16(pa0, vb0, fzero, 0, 0, 0);
        oacc[0][1] = __builtin_amdgcn_mfma_f32_16x16x32_bf16(pa0, vb1, fzero, 0, 0, 0);
        oacc[1][0] = __builtin_amdgcn_mfma_f32_16x16x32_bf16(pa1, vb0, fzero, 0, 0, 0);
        oacc[1][1] = __builtin_amdgcn_mfma_f32_16x16x32_bf16(pa1, vb1, fzero, 0, 0, 0);
    }
    __syncthreads();   // B5 (Pm/vT reads done -> obf may overwrite)

    {
        const int hb = wv4 * DKK;
#pragma unroll
        for (int mt = 0; mt < 2; mt++)
#pragma unroll
            for (int nt = 0; nt < 2; nt++)
#pragma unroll
                for (int r = 0; r < 4; r++)
                    obf[mt * 16 + quad * 4 + r][hb + nt * 16 + col] =
                        __float2bfloat16(oacc[mt][nt][r]);
    }
    __syncthreads();   // B6

    // ===== attn_fc: X = O @ afwT + afb + z; then LN -> xb =====
    {
        const bf16* AF = aw + 4 * (DD * DD);
        f32x4 facc[2][2];
#pragma unroll
        for (int mt = 0; mt < 2; mt++)
#pragma unroll
            for (int nt = 0; nt < 2; nt++) facc[mt][nt] = fzero;
#pragma unroll
        for (int kk = 0; kk < 4; kk++) {
            const int k0 = kk * 32 + quad * 8;
            const s16x8 a0 = *(const s16x8*)&obf[col][k0];
            const s16x8 a1 = *(const s16x8*)&obf[16 + col][k0];
#pragma unroll
            for (int nt = 0; nt < 2; nt++) {
                const int n = (wv4 * 2 + nt) * 16 + col;
                const s16x8 b = *(const s16x8*)&AF[n * DD + k0];
                facc[0][nt] = __builtin_amdgcn_mfma_f32_16x16x32_bf16(a0, b, facc[0][nt], 0, 0, 0);
                facc[1][nt] = __builtin_amdgcn_mfma_f32_16x16x32_bf16(a1, b, facc[1][nt], 0, 0, 0);
            }
        }
        __syncthreads();   // B7 (obf reads done -> us may overwrite)

#pragma unroll
        for (int mt = 0; mt < 2; mt++)
#pragma unroll
            for (int nt = 0; nt < 2; nt++) {
                const int n = (wv4 * 2 + nt) * 16 + col;
                const float bias = afb[n];
#pragma unroll
                for (int r = 0; r < 4; r++) {
                    const int i = mt * 16 + quad * 4 + r;
                    if (i >= KK) continue;
                    us[i][n] = facc[mt][nt][r] + bias + __bfloat162float(zs[i][n]);
                }
            }
    }
    __syncthreads();   // B8

    for (int i = wv4; i < KK; i += 4) {        // attn LN -> xb (vT dead)
        const float a0 = us[i][lane], a1 = us[i][lane + 64];
        const float s  = wave_sum(a0 + a1);
        const float sq = wave_sum(a0 * a0 + a1 * a1);
        const float mean = s * (1.0f / DD);
        const float var  = sq * (1.0f / DD) - mean * mean;
        const float inv  = rsqrtf(var + 1e-5f);
        xb[i][lane]      = __float2bfloat16((a0 - mean) * inv * alng[lane] + alnb[lane]);
        xb[i][lane + 64] = __float2bfloat16((a1 - mean) * inv * alng[lane + 64] + alnb[lane + 64]);
    }
    __syncthreads();   // B9 (us dead -> h1 region free)

    // ===== FFN in two 256-col chunks; acc2 accumulates across chunks =====
    f32x4 acc2[2][2];
#pragma unroll
    for (int mt = 0; mt < 2; mt++)
#pragma unroll
        for (int nt = 0; nt < 2; nt++) acc2[mt][nt] = fzero;

#pragma unroll
    for (int ch = 0; ch < 2; ch++) {
        {   // phase A: h1 = relu(x @ W1 + b1), cols [ch*256, ch*256+256)
            f32x4 acc[2][4];
#pragma unroll
            for (int mt = 0; mt < 2; mt++)
#pragma unroll
                for (int nt = 0; nt < 4; nt++) acc[mt][nt] = fzero;
#pragma unroll
            for (int kk = 0; kk < 4; kk++) {
                const int k0 = kk * 32 + quad * 8;
                const s16x8 a0 = *(const s16x8*)&xb[col][k0];
                const s16x8 a1 = *(const s16x8*)&xb[16 + col][k0];   // rows>=20 alias (masked)
#pragma unroll
                for (int nt = 0; nt < 4; nt++) {
                    const int n = ch * 256 + wv4 * 64 + nt * 16 + col;
                    const s16x8 b = *(const s16x8*)&w1t[n * DD + k0];
                    acc[0][nt] = __builtin_amdgcn_mfma_f32_16x16x32_bf16(a0, b, acc[0][nt], 0, 0, 0);
                    acc[1][nt] = __builtin_amdgcn_mfma_f32_16x16x32_bf16(a1, b, acc[1][nt], 0, 0, 0);
                }
            }
#pragma unroll
            for (int nt = 0; nt < 4; nt++) {
                const int nl = wv4 * 64 + nt * 16 + col;
                const float bias = b1[ch * 256 + nl];
#pragma unroll
                for (int mt = 0; mt < 2; mt++)
#pragma unroll
                    for (int r = 0; r < 4; r++) {
                        const int row = mt * 16 + quad * 4 + r;
                        if (row < KK)
                            h1[row][nl] = __float2bfloat16(fmaxf(acc[mt][nt][r] + bias, 0.f));
                    }
            }
        }
        __syncthreads();   // B10/B12

        {   // phase B: acc2 += h1 @ W2[k-chunk]
#pragma unroll
            for (int kk = 0; kk < 8; kk++) {
                const int k0l = kk * 32 + quad * 8;
                const s16x8 a0 = *(const s16x8*)&h1[col][k0l];
                const s16x8 a1 = *(const s16x8*)&h1[16 + col][k0l];  // rows>=20 garbage (masked)
#pragma unroll
                for (int nt = 0; nt < 2; nt++) {
                    const int n = wv4 * 32 + nt * 16 + col;
                    const s16x8 b = *(const s16x8*)&w2t[n * HIDD + ch * 256 + k0l];
                    acc2[0][nt] = __builtin_amdgcn_mfma_f32_16x16x32_bf16(a0, b, acc2[0][nt], 0, 0, 0);
                    acc2[1][nt] = __builtin_amdgcn_mfma_f32_16x16x32_bf16(a1, b, acc2[1][nt], 0, 0, 0);
                }
            }
        }
        __syncthreads();   // B11/B13 (h1 reads done)
    }

    // FFN epilogue: u = acc2 + b2 + x
#pragma unroll
    for (int mt = 0; mt < 2; mt++)
#pragma unroll
        for (int nt = 0; nt < 2; nt++) {
            const int n = wv4 * 32 + nt * 16 + col;
            const float bias = b2[n];
#pragma unroll
            for (int r = 0; r < 4; r++) {
                const int i = mt * 16 + quad * 4 + r;
                if (i >= KK) continue;
                us[i][n] = acc2[mt][nt][r] + bias + __bfloat162float(xb[i][n]);
            }
        }
    __syncthreads();   // B14

    for (int i = wv4; i < KK; i += 4) {       // FFN LN, in place (x in f32)
        const float a0 = us[i][lane], a1 = us[i][lane + 64];
        const float s  = wave_sum(a0 + a1);
        const float sq = wave_sum(a0 * a0 + a1 * a1);
        const float mean = s * (1.0f / DD);
        const float var  = sq * (1.0f / DD) - mean * mean;
        const float inv  = rsqrtf(var + 1e-5f);
        us[i][lane]      = (a0 - mean) * inv * flng[lane] + flnb[lane];
        us[i][lane + 64] = (a1 - mean) * inv * flng[lane + 64] + flnb[lane + 64];
    }
    __syncthreads();   // B15

    // ===== fuse: [x_self | mean(neighbors)] @ fw + gelu + residual + LN =====
    if (tid < DD) {
        fused[tid] = us[19][tid];
    } else {
        const int d = tid - DD;
        float nb = 0.f;
#pragma unroll
        for (int i = 0; i < KK - 1; i++) nb += us[i][d];
        fused[DD + d] = nb * (1.0f / (KK - 1));
    }
    __syncthreads();   // B16

    {
        const int d = tid & 127, hb2 = tid >> 7;
        float a = 0.f;
#pragma unroll 8
        for (int ci = 0; ci < 128; ci++) {
            const int c = hb2 * 128 + ci;
            a += fused[c] * __bfloat162float(fwb[c * DD + d]);
        }
        part[hb2][d] = a;
    }
    __syncthreads();   // B17

    float y = 0.f;
    if (tid < DD) {
        y = geluf(part[0][tid] + part[1][tid] + fb[tid]) + nhs[base + (KK - 1) * DD + tid];
        float s = y, sq = y * y;
#pragma unroll
        for (int o = 32; o > 0; o >>= 1) {
            s += __shfl_down(s, o);
            sq += __shfl_down(sq, o);
        }
        const int wid = tid >> 6, ln = tid & 63;
        if (ln == 0) { red[wid] = s; red[2 + wid] = sq; }
    }
    __syncthreads();   // B18
    if (tid < DD) {
        const float tsm = red[0] + red[1], tsq = red[2] + red[3];
        const float mean = tsm * (1.0f / DD);
        const float var  = tsq * (1.0f / DD) - mean * mean;
        const float inv  = rsqrtf(var + 1e-5f);
        out[node * DD + tid] = (y - mean) * inv * olng[tid] + olnb[tid];
    }
}

// ---------------------------------------------------------------------------
extern "C" void kernel_launch(void* const* d_in, const int* in_sizes, int n_in,
                              void* d_out, int out_size, void* d_ws, size_t ws_size,
                              hipStream_t stream)
{
    const float* nhs   = (const float*)d_in[0];
    const float* t     = (const float*)d_in[1];
    const float* tnow  = (const float*)d_in[2];
    const float* ef    = (const float*)d_in[3];
    const float* freq  = (const float*)d_in[4];
    const float* phase = (const float*)d_in[5];
    const float* ew    = (const float*)d_in[6];
    const float* eb    = (const float*)d_in[7];
    const float* wq    = (const float*)d_in[8];
    const float* wk    = (const float*)d_in[9];
    const float* wv    = (const float*)d_in[10];
    const float* wqs   = (const float*)d_in[11];
    const float* afw   = (const float*)d_in[12];
    const float* afb   = (const float*)d_in[13];
    const float* alng  = (const float*)d_in[14];
    const float* alnb  = (const float*)d_in[15];
    const float* w1    = (const float*)d_in[16];
    const float* b1    = (const float*)d_in[17];
    const float* w2    = (const float*)d_in[18];
    const float* b2    = (const float*)d_in[19];
    const float* flng  = (const float*)d_in[20];
    const float* flnb  = (const float*)d_in[21];
    const float* fw    = (const float*)d_in[22];
    const float* fb    = (const float*)d_in[23];
    const float* olng  = (const float*)d_in[24];
    const float* olnb  = (const float*)d_in[25];
    float* out = (float*)d_out;

    bf16* w1t = (bf16*)d_ws;                 // [512][128]  131072 B
    bf16* w2t = w1t + HIDD * DD;             // [128][512]  131072 B
    bf16* aw  = w2t + DD * HIDD;             // 8 x 16384 bf16 (6 transposed + fw)

    k0_conv<<<dim3(2 * HIDD * DD / 256), dim3(256), 0, stream>>>(w1, w2, w1t, w2t);
    k0b_conv<<<dim3(8 * DD * DD / 256), dim3(256), 0, stream>>>(wq, wk, wv, wqs, afw, ew, fw, aw);
    k_node<<<dim3(N_NODES), dim3(256), 0, stream>>>(
        nhs, t, tnow, ef, freq, phase, eb, aw, afb, alng, alnb,
        w1t, b1, w2t, b2, flng, flnb, fb, olng, olnb, out);
}